// Round 11
// baseline (22.658 us; speedup 1.0000x reference)
//
#include <hip/hip_runtime.h>
#include <hip/hip_bf16.h>

#define NN 262144
#define DD 32
#define HH 31
#define KK 21
#define ROWS 128                 // rows per block (2 threads per row)
#define FSTRIDE 18               // u32 words per row in LDS (72 B)

typedef __attribute__((ext_vector_type(8))) short bf16x8;
typedef __attribute__((ext_vector_type(4))) float f32x4;
typedef __attribute__((ext_vector_type(2))) unsigned int u32x2;
typedef __attribute__((ext_vector_type(4))) unsigned int u32x4;

static __device__ __forceinline__ unsigned short f2bf(float f) {
    __hip_bfloat16 h = __float2bfloat16(f);      // round-to-nearest-even
    return __builtin_bit_cast(unsigned short, h);
}
static __device__ __forceinline__ unsigned pack2(float lo, float hi) {
    return (unsigned)f2bf(lo) | ((unsigned)f2bf(hi) << 16);
}

// ---------------- Prep: per-lane fragment/const tables (tiny) ----------------
__global__ __launch_bounds__(64) void prep_kernel(
    const float* __restrict__ W1, const float* __restrict__ b1,
    const float* __restrict__ W2,
    bf16x8* __restrict__ A0tab, bf16x8* __restrict__ A1tab,
    f32x4* __restrict__ cq0b, f32x4* __restrict__ cq0w,
    f32x4* __restrict__ cq1b, f32x4* __restrict__ cq1w)
{
    const int k = (int)blockIdx.x;
    const int lane = (int)threadIdx.x;
    const int lrow = lane & 15, lgrp = lane >> 4;
    const float* __restrict__ W1k = W1 + k * HH * HH;
    const int e0 = lrow, e1 = 16 + lrow;

    bf16x8 A0, A1;
    #pragma unroll
    for (int j = 0; j < 4; ++j) {
        const int d1 = 4 * lgrp + j;
        const int d2 = 16 + 4 * lgrp + j;
        A0[j]     = (short)f2bf(W1k[d1 * HH + e0]);
        A0[4 + j] = (d2 < HH) ? (short)f2bf(W1k[d2 * HH + e0]) : (short)0;
        A1[j]     = (e1 < HH) ? (short)f2bf(W1k[d1 * HH + e1]) : (short)0;
        A1[4 + j] = (e1 < HH && d2 < HH) ? (short)f2bf(W1k[d2 * HH + e1]) : (short)0;
    }
    A0tab[k * 64 + lane] = A0;
    A1tab[k * 64 + lane] = A1;

    f32x4 b0v, w0v, b1v, w1v;
    #pragma unroll
    for (int r = 0; r < 4; ++r) {
        const int e = 4 * lgrp + r, eb = 16 + e;
        b0v[r] = b1[k * HH + e];
        w0v[r] = W2[k * HH + e];
        b1v[r] = (eb < HH) ? b1[k * HH + eb] : 0.0f;
        w1v[r] = (eb < HH) ? W2[k * HH + eb] : 0.0f;
    }
    cq0b[k * 64 + lane] = b0v;
    cq0w[k * 64 + lane] = w0v;
    cq1b[k * 64 + lane] = b1v;
    cq1w[k * 64 + lane] = w1v;
}

// ---------------- Fused: coalesced load + sort + MFMA, 32 waves/CU ----------
__global__ __launch_bounds__(256, 8) void fused_kernel(
    const float* __restrict__ x,
    const float* __restrict__ a,
    const float* __restrict__ b,
    const float* __restrict__ b2,
    const bf16x8* __restrict__ A0tab, const bf16x8* __restrict__ A1tab,
    const f32x4* __restrict__ cq0b, const f32x4* __restrict__ cq0w,
    const f32x4* __restrict__ cq1b, const f32x4* __restrict__ cq1w,
    float* __restrict__ out)
{
    __shared__ unsigned fbf[ROWS * FSTRIDE];   // feats as packed bf16 pairs
    __shared__ int cnt[KK];
    __shared__ int rnk[KK];
    __shared__ int sbase[KK];
    __shared__ int tstart[KK + 1];
    __shared__ unsigned short sorted[ROWS];

    const int tid = (int)threadIdx.x;
    const int lane = tid & 63;
    const int rowbase = (int)blockIdx.x * ROWS;

    if (tid < KK) { cnt[tid] = 0; rnk[tid] = 0; }
    __syncthreads();

    // ---- Phase 1: perfectly coalesced 64 B/lane (wave reads 4 KB span) ----
    // chunk tid covers row r = tid/2, half = tid&1 (elems 16*half .. 16*half+15)
    const int r    = tid >> 1;
    const int half = tid & 1;
    const float4* __restrict__ p =
        reinterpret_cast<const float4*>(x) + (size_t)blockIdx.x * (ROWS * DD / 4) + tid * 4;
    float4 c[4];
    #pragma unroll
    for (int i = 0; i < 4; ++i) c[i] = p[i];

    // even lane i gets odd lane i+1's first element (x-elem 16 of the row)
    const float e16 = __shfl(c[0].x, lane + 1);

    // bucket from t (only meaningful on even threads; odd discards)
    const float t = c[0].x;
    const float edges[KK + 1] = {
        0.0f, 0.1f, 0.2f, 0.3f, 0.4f, 0.5f, 0.6f, 0.7f, 0.8f, 0.9f, 1.0f,
        1.1f, 1.2f, 1.3f, 1.4f, 1.5f, 1.6f, 1.7f, 1.8f, 1.9f, 2.0f, 1000.0f
    };
    int kq = -1;
    #pragma unroll
    for (int j = 0; j < KK; ++j)
        if (t > edges[j] && t <= edges[j + 1]) kq = j;

    // feats -> packed bf16 LDS. even: feats 0..15 (x-elems 1..16);
    // odd: feats 16..30 (x-elems 17..31), feats31 = 0.
    unsigned* __restrict__ frow = fbf + r * FSTRIDE + half * 8;
    if (half == 0) {
        float f[16];
        #pragma unroll
        for (int j = 0; j < 15; ++j) {
            const float xe = (j + 1 < 4)  ? ((j + 1 == 1) ? c[0].y : (j + 1 == 2) ? c[0].z : c[0].w)
                                          : ((const float*)c)[j + 1];
            f[j] = fmaf(xe, a[j], b[j]);
        }
        f[15] = fmaf(e16, a[15], b[15]);
        #pragma unroll
        for (int s = 0; s < 8; ++s) frow[s] = pack2(f[2 * s], f[2 * s + 1]);
    } else {
        float f[16];
        #pragma unroll
        for (int j = 0; j < 15; ++j) {
            const float xe = ((const float*)c)[j + 1];      // elem 17+j
            f[j] = fmaf(xe, a[16 + j], b[16 + j]);
        }
        f[15] = 0.0f;
        #pragma unroll
        for (int s = 0; s < 8; ++s) frow[s] = pack2(f[2 * s], f[2 * s + 1]);
    }

    if (half == 0) {
        if (kq >= 0) atomicAdd(&cnt[kq], 1);
        else out[rowbase + r] = 0.0f;
    }
    __syncthreads();

    // ---- Phase 2: wave-parallel scan (lanes 0..21 of wave 0) ----
    if (tid < 64) {
        const int j = tid;
        const int c0 = (j < KK) ? cnt[j] : 0;
        const int t0 = (j < KK) ? ((c0 + 15) >> 4) : 0;
        int sc = c0, st = t0;
        #pragma unroll
        for (int off = 1; off < 32; off <<= 1) {
            const int vc = __shfl_up(sc, off);
            const int vt = __shfl_up(st, off);
            if (j >= off) { sc += vc; st += vt; }
        }
        if (j < KK) { sbase[j] = sc - c0; tstart[j] = st - t0; }
        if (j == KK) tstart[KK] = st;       // total tiles
    }
    __syncthreads();
    if (half == 0 && kq >= 0) {
        const int rr = atomicAdd(&rnk[kq], 1);
        sorted[sbase[kq] + rr] = (unsigned short)r;
    }
    __syncthreads();

    // ---- Phase 3: MFMA over per-bucket 16-row tiles ----
    const int wave = tid >> 6;
    const int lrow = lane & 15;
    const int lgrp = lane >> 4;

    const int NT = tstart[KK];
    const int ts_l = tstart[(lane <= KK) ? lane : KK];

    for (int tix = wave; tix < NT; tix += 4) {
        const unsigned long long m = __ballot(ts_l <= tix);
        const int k = __builtin_amdgcn_readfirstlane(__popcll(m) - 1);

        const int sb = sbase[k];
        const int cn = cnt[k];
        const int r0 = (tix - tstart[k]) * 16;
        const int rl = r0 + lrow;

        const int R = sorted[sb + ((rl < cn) ? rl : 0)];

        // B fragment: 2x ds_read_b64 of pre-rounded bf16 feats
        const unsigned* __restrict__ fr = fbf + R * FSTRIDE;
        const u32x2 wlo = *(const u32x2*)(fr + 2 * lgrp);
        const u32x2 whi = *(const u32x2*)(fr + 8 + 2 * lgrp);
        u32x4 bw;
        bw[0] = wlo[0]; bw[1] = wlo[1]; bw[2] = whi[0]; bw[3] = whi[1];
        const bf16x8 B = __builtin_bit_cast(bf16x8, bw);

        const bf16x8 A0 = A0tab[k * 64 + lane];
        const bf16x8 A1 = A1tab[k * 64 + lane];
        const f32x4 cb0 = cq0b[k * 64 + lane];
        const f32x4 cw0 = cq0w[k * 64 + lane];
        const f32x4 cb1 = cq1b[k * 64 + lane];
        const f32x4 cw1 = cq1w[k * 64 + lane];
        const float b2k = b2[k];

        f32x4 acc0 = {0.0f, 0.0f, 0.0f, 0.0f};
        f32x4 acc1 = {0.0f, 0.0f, 0.0f, 0.0f};
        acc0 = __builtin_amdgcn_mfma_f32_16x16x32_bf16(A0, B, acc0, 0, 0, 0);
        acc1 = __builtin_amdgcn_mfma_f32_16x16x32_bf16(A1, B, acc1, 0, 0, 0);

        float S = 0.0f;
        #pragma unroll
        for (int rr = 0; rr < 4; ++rr) {
            const float h0 = acc0[rr] + cb0[rr];
            const float q0 = (h0 >= 0.0f) ? h0 : 0.1f * h0;
            S = fmaf(q0, cw0[rr], S);
            const float h1 = acc1[rr] + cb1[rr];
            const float q1 = (h1 >= 0.0f) ? h1 : 0.1f * h1;
            S = fmaf(q1, cw1[rr], S);
        }
        S += __shfl_xor(S, 16);
        S += __shfl_xor(S, 32);

        if (lgrp == 0 && rl < cn) out[rowbase + R] = S + b2k;
    }
}

extern "C" void kernel_launch(void* const* d_in, const int* in_sizes, int n_in,
                              void* d_out, int out_size, void* d_ws, size_t ws_size,
                              hipStream_t stream) {
    const float* x  = (const float*)d_in[0];
    const float* a  = (const float*)d_in[1];
    const float* b  = (const float*)d_in[2];
    const float* W1 = (const float*)d_in[3];
    const float* b1 = (const float*)d_in[4];
    const float* W2 = (const float*)d_in[5];
    const float* b2 = (const float*)d_in[6];
    float* out = (float*)d_out;

    char* ws = (char*)d_ws;
    bf16x8* A0tab = (bf16x8*)ws;                       // 21*64*16B
    bf16x8* A1tab = A0tab + KK * 64;
    f32x4* cq0b = (f32x4*)(A1tab + KK * 64);
    f32x4* cq0w = cq0b + KK * 64;
    f32x4* cq1b = cq0w + KK * 64;
    f32x4* cq1w = cq1b + KK * 64;

    hipLaunchKernelGGL(prep_kernel, dim3(KK), dim3(64), 0, stream,
                       W1, b1, W2, A0tab, A1tab, cq0b, cq0w, cq1b, cq1w);

    hipLaunchKernelGGL(fused_kernel, dim3(NN / ROWS), dim3(256), 0, stream,
                       x, a, b, b2, A0tab, A1tab, cq0b, cq0w, cq1b, cq1w, out);
}